// Round 7
// baseline (497.737 us; speedup 1.0000x reference)
//
#include <hip/hip_runtime.h>

typedef _Float16 f16x8 __attribute__((ext_vector_type(8)));
typedef _Float16 f16x4 __attribute__((ext_vector_type(4)));
typedef __fp16  fp16x2 __attribute__((ext_vector_type(2)));
typedef float f32x4 __attribute__((ext_vector_type(4)));
typedef unsigned int u32;

#define ROWS 64
#define THREADS 1024

// ---------------------------------------------------------------------------
// Prep: convert W1/W2/W3 (f32, [K][C] row-major) into f16 fragment-linear
// layout WF[ct][kt][lane][8], applying block-diag masks by only gathering
// in-block K. Fragment mapping (used as MFMA *A* operand, M-dim = out col):
//   col = ct*16 + (lane&15), k = kbase + kt*32 + (lane>>4)*8 + j
// ---------------------------------------------------------------------------
__global__ __launch_bounds__(512) void pack_weights(
    const float* __restrict__ W1, const float* __restrict__ W2,
    const float* __restrict__ W3, _Float16* __restrict__ WF1,
    _Float16* __restrict__ WF2, _Float16* __restrict__ WF3) {
  int t = blockIdx.x * 512 + threadIdx.x;
  const float* src; _Float16* dst; int idx, ct, kt, lane, kbase;
  if (t < 131072) {                       // W1: 64 ct * 32 kt * 64 lanes
    idx = t; src = W1; dst = WF1;
    ct = idx >> 11; kt = (idx >> 6) & 31; lane = idx & 63; kbase = 0;
  } else if (t < 196608) {                // W2: 64 ct * 16 kt * 64 lanes
    idx = t - 131072; src = W2; dst = WF2;
    ct = idx >> 10; kt = (idx >> 6) & 15; lane = idx & 63;
    kbase = (ct >= 32) ? 512 : 0;         // 2 blocks of 512
  } else {                                // W3: 64 ct * 8 kt * 64 lanes
    idx = t - 196608; src = W3; dst = WF3;
    ct = idx >> 9; kt = (idx >> 6) & 7; lane = idx & 63;
    kbase = (ct >> 4) << 8;               // 4 blocks of 256
  }
  int c  = ct * 16 + (lane & 15);
  int k0 = kbase + kt * 32 + ((lane >> 4) << 3);
  f16x8 v;
#pragma unroll
  for (int j = 0; j < 8; ++j) v[j] = (_Float16)src[(size_t)(k0 + j) * 1024 + c];
  *reinterpret_cast<f16x8*>(dst + (size_t)idx * 8) = v;
}

// ---------------------------------------------------------------------------
// One MFMA layer, TRANSPOSED operand order: D = W_frag * h_frag.
//   A (W): M-dim = out col,  row = lane&15, k = kt*32+(lane>>4)*8+j
//   B (h): N-dim = data row, col = lane&15, same k mapping (ds_read_b128)
//   D:     col(lane&15) = data row r, row((lane>>4)*4+i) = out col c
// 16 waves; wave wid owns out-cols [wid*64, +64): acc[4 cf][4 rf] (64 AGPR).
// Single-buffered W and h: latency is covered by 4 waves/SIMD (TLP), not
// per-wave pipelining — the W-dbuf at this occupancy would spill (128-reg
// budget at 4 waves/EU; acc 64 + W 16 + h 16 + addr ~16 = ~112).
// ---------------------------------------------------------------------------
template <int KT>
__device__ __forceinline__ void layer_mfma(char* hb, const _Float16* __restrict__ WF,
                                           const float* __restrict__ bias,
                                           int wid, int lane, int kbase) {
  f32x4 acc[4][4];
#pragma unroll
  for (int cf = 0; cf < 4; ++cf)
#pragma unroll
    for (int rf = 0; rf < 4; ++rf) acc[cf][rf] = f32x4{0.f, 0.f, 0.f, 0.f};

  const f16x8* wf = reinterpret_cast<const f16x8*>(WF) +
                    (u32)(wid * 4 * KT * 64 + lane);
  const int arow = lane & 15;
  const int koff = (lane >> 4) << 3;
  const u32 abase = (u32)(arow * 2048);
  const u32 axor  = (u32)((arow & 7) << 4);   // (row&7)==(arow&7): rf*16 ≡ 0 mod 8

#pragma unroll 1
  for (int kt = 0; kt < KT; ++kt) {
    f16x8 w[4];
#pragma unroll
    for (int cf = 0; cf < 4; ++cf)
      w[cf] = wf[(u32)(cf * KT) * 64u + (u32)kt * 64u];   // issue W first (L2)
    u32 kb = (u32)((kbase + kt * 32 + koff) * 2);
    f16x8 h[4];
#pragma unroll
    for (int rf = 0; rf < 4; ++rf) {
      u32 addr = ((u32)(rf * 32768) + abase + kb) ^ axor;
      h[rf] = *reinterpret_cast<const f16x8*>(hb + addr);
    }
    __builtin_amdgcn_s_setprio(1);
#pragma unroll
    for (int cf = 0; cf < 4; ++cf)
#pragma unroll
      for (int rf = 0; rf < 4; ++rf)
        acc[cf][rf] = __builtin_amdgcn_mfma_f32_16x16x32_f16(w[cf], h[rf],
                                                             acc[cf][rf], 0, 0, 0);
    __builtin_amdgcn_s_setprio(0);
  }

  __syncthreads();                          // all waves done READING h
  const int csub = (lane >> 4) << 2;        // 0,4,8,12
  const int rr   = lane & 15;
#pragma unroll
  for (int cf = 0; cf < 4; ++cf) {
    int c0 = wid * 64 + cf * 16 + csub;
    f32x4 bb = *reinterpret_cast<const f32x4*>(bias + c0);
#pragma unroll
    for (int rf = 0; rf < 4; ++rf) {
      int r = rf * 16 + rr;
      float s0 = __sinf(acc[cf][rf][0] + bb[0]);
      float s1 = __sinf(acc[cf][rf][1] + bb[1]);
      float s2 = __sinf(acc[cf][rf][2] + bb[2]);
      float s3 = __sinf(acc[cf][rf][3] + bb[3]);
      union { fp16x2 h2[2]; f16x4 v; } pk;
      pk.h2[0] = __builtin_amdgcn_cvt_pkrtz(s0, s1);
      pk.h2[1] = __builtin_amdgcn_cvt_pkrtz(s2, s3);
      u32 addr = ((u32)(r * 2048 + c0 * 2)) ^ ((u32)((r & 7) << 4));
      *reinterpret_cast<f16x4*>(hb + addr) = pk.v;
    }
  }
  __syncthreads();                          // h_out visible before next layer
}

// ---------------------------------------------------------------------------
// Fused forward: 64 rows per WG, h lives in LDS for the whole network.
// 1024 threads = 16 waves = 4 waves/SIMD for latency hiding.
// ---------------------------------------------------------------------------
__global__
__attribute__((amdgpu_flat_work_group_size(1024, 1024), amdgpu_waves_per_eu(4, 4)))
void bspinn_fused(
    const float* __restrict__ X, const float* __restrict__ lb,
    const float* __restrict__ ub,
    const float* __restrict__ W0, const float* __restrict__ b0,
    const _Float16* __restrict__ WF1, const float* __restrict__ b1,
    const _Float16* __restrict__ WF2, const float* __restrict__ b2,
    const _Float16* __restrict__ WF3, const float* __restrict__ b3,
    const float* __restrict__ W4, const float* __restrict__ b4,
    float* __restrict__ out) {
  __shared__ alignas(16) char hb[ROWS * 2048];   // 128 KiB, f16, swizzled
  __shared__ float xs[ROWS * 4];
  __shared__ float partials[16 * ROWS];

  const int tid  = threadIdx.x;
  const int lane = tid & 63;
  const int wid  = tid >> 6;
  const int r0   = blockIdx.x * ROWS;

  if (tid < ROWS * 3) {                      // stage + normalize X
    int r = tid / 3, j = tid - r * 3;
    float x = X[(size_t)r0 * 3 + tid];
    xs[r * 4 + j] = 2.0f * (x - lb[j]) / (ub[j] - lb[j]) - 1.0f;
  }
  __syncthreads();

  // ---- layer 1 (K=3, VALU): each thread owns 1 col x 64 rows ----
  {
    int c0 = tid;
    float wa0 = W0[c0];
    float wa1 = W0[1024 + c0];
    float wa2 = W0[2048 + c0];
    float ba = b0[c0];
#pragma unroll 4
    for (int r = 0; r < ROWS; ++r) {
      float x0 = xs[r * 4], x1 = xs[r * 4 + 1], x2 = xs[r * 4 + 2];
      float va = __sinf(fmaf(x2, wa2, fmaf(x1, wa1, fmaf(x0, wa0, ba))));
      u32 addr = ((u32)(r * 2048 + c0 * 2)) ^ ((u32)((r & 7) << 4));
      *reinterpret_cast<_Float16*>(hb + addr) = (_Float16)va;
    }
  }
  __syncthreads();

  layer_mfma<32>(hb, WF1, b1, wid, lane, 0);                  // dense 1024
  layer_mfma<16>(hb, WF2, b2, wid, lane, (wid >> 3) * 512);   // 2 blocks
  layer_mfma<8 >(hb, WF3, b3, wid, lane, (wid >> 2) * 256);   // 4 blocks

  // ---- layer 5 (M=1, VALU): lane = row -> swizzled conflict-light reads ----
  {
    int r = lane, seg = wid;                 // 16 segs of 64 K each
    u32 rb = (u32)(r * 2048);
    u32 xr = (u32)((r & 7) << 4);
    float s = 0.f;
#pragma unroll
    for (int kk = 0; kk < 64; kk += 8) {
      int k = seg * 64 + kk;
      f16x8 v = *reinterpret_cast<const f16x8*>(hb + ((rb + (u32)(k * 2)) ^ xr));
#pragma unroll
      for (int j = 0; j < 8; ++j) s = fmaf((float)v[j], W4[k + j], s);
    }
    partials[seg * 64 + r] = s;
  }
  __syncthreads();
  if (tid < ROWS) {
    float s = b4[0];
#pragma unroll
    for (int g = 0; g < 16; ++g) s += partials[g * 64 + tid];
    out[r0 + tid] = s;
  }
}

extern "C" void kernel_launch(void* const* d_in, const int* in_sizes, int n_in,
                              void* d_out, int out_size, void* d_ws, size_t ws_size,
                              hipStream_t stream) {
  const float* X  = (const float*)d_in[0];
  const float* lb = (const float*)d_in[1];
  const float* ub = (const float*)d_in[2];
  const float* W0 = (const float*)d_in[3];
  const float* b0 = (const float*)d_in[4];
  const float* W1 = (const float*)d_in[5];
  const float* b1 = (const float*)d_in[6];
  const float* W2 = (const float*)d_in[7];
  const float* b2 = (const float*)d_in[8];
  const float* W3 = (const float*)d_in[9];
  const float* b3 = (const float*)d_in[10];
  const float* W4 = (const float*)d_in[11];
  const float* b4 = (const float*)d_in[12];
  float* out = (float*)d_out;

  _Float16* WF1 = (_Float16*)d_ws;                                    // 2 MiB
  _Float16* WF2 = (_Float16*)((char*)d_ws + 2097152);                 // 1 MiB
  _Float16* WF3 = (_Float16*)((char*)d_ws + 2097152 + 1048576);       // 512 KiB

  hipLaunchKernelGGL(pack_weights, dim3(448), dim3(512), 0, stream,
                     W1, W2, W3, WF1, WF2, WF3);
  hipLaunchKernelGGL(bspinn_fused, dim3(131072 / ROWS), dim3(THREADS), 0, stream,
                     X, lb, ub, W0, b0, WF1, b1, WF2, b2, WF3, b3, W4, b4, out);
}